// Round 2
// baseline (353.903 us; speedup 1.0000x reference)
//
#include <hip/hip_runtime.h>
#include <hip/hip_fp16.h>
#include <math.h>

#define NB 4
#define NR 4096
#define NS 48
#define PLANE_ELEMS (65536*32)   // H*W*C per (b,plane) (elements)

typedef _Float16 f16x8 __attribute__((ext_vector_type(8)));
typedef float    f32x4 __attribute__((ext_vector_type(4)));

__device__ __forceinline__ float coarse_depth(float cam, int i) {
    float nearv = cam - 0.5f;
    float farv  = cam + 0.5f;
    float t = ((float)i + 0.5f) / 48.0f;
    return nearv + (farv - nearv) * t;
}
__device__ __forceinline__ float softplusf(float x) {
    return fmaxf(x, 0.0f) + __logf(1.0f + __expf(-fabsf(x)));
}
__device__ __forceinline__ float sigmoidf(float x) {
    return 1.0f / (1.0f + __expf(-x));
}

// K0: transpose planes [bp][C][H][W] f32 -> [bp][H][W][C] f16 (64B/texel).
// Vectorized: float4 global loads, b128 LDS writes, dwordx4 stores.
// Block 3072 packs w1 into MFMA A-fragment layout (unchanged).
__global__ __launch_bounds__(256) void k_transpose(const float* __restrict__ src,
                                                   __half* __restrict__ dst,
                                                   const float* __restrict__ w1,
                                                   unsigned* __restrict__ w1frag) {
    if (blockIdx.x == 3072) {
        int t = threadIdx.x;
        for (int f = t; f < 1024; f += 256) {
            int ht = f >> 8, rem = f & 255, lane = rem >> 2, qq = rem & 3;
            int quad = lane >> 4, m = lane & 15;
            int k0 = quad*8 + 2*qq;
            __half lo = __float2half_rn(w1[(k0+0)*64 + ht*16 + m]);
            __half hi = __float2half_rn(w1[(k0+1)*64 + ht*16 + m]);
            w1frag[f] = (unsigned)__half_as_ushort(lo)
                      | ((unsigned)__half_as_ushort(hi) << 16);
        }
        return;
    }
    // tile32[cp][x]: packed u32 = half(c=2cp,x) | half(c=2cp+1,x)<<16
    __shared__ unsigned tile32[16*260];
    int bp = blockIdx.x >> 8;
    int y  = blockIdx.x & 255;
    int t  = threadIdx.x;
    const float4* s4 = reinterpret_cast<const float4*>(
        src + (size_t)bp*PLANE_ELEMS + (size_t)y*256);
    #pragma unroll
    for (int it = 0; it < 4; ++it) {
        int idx = it*256 + t;
        int cp = idx >> 6, x4 = idx & 63;          // cp uniform per wave
        float4 a = s4[(size_t)(2*cp)*16384 + x4];  // channel 2cp, 4 pixels
        float4 b = s4[(size_t)(2*cp+1)*16384 + x4];
        unsigned u0 = (unsigned)__half_as_ushort(__float2half_rn(a.x))
                    | ((unsigned)__half_as_ushort(__float2half_rn(b.x)) << 16);
        unsigned u1 = (unsigned)__half_as_ushort(__float2half_rn(a.y))
                    | ((unsigned)__half_as_ushort(__float2half_rn(b.y)) << 16);
        unsigned u2 = (unsigned)__half_as_ushort(__float2half_rn(a.z))
                    | ((unsigned)__half_as_ushort(__float2half_rn(b.z)) << 16);
        unsigned u3 = (unsigned)__half_as_ushort(__float2half_rn(a.w))
                    | ((unsigned)__half_as_ushort(__float2half_rn(b.w)) << 16);
        *reinterpret_cast<uint4*>(&tile32[cp*260 + x4*4]) = make_uint4(u0,u1,u2,u3);
    }
    __syncthreads();
    uint4* d4 = reinterpret_cast<uint4*>(
        reinterpret_cast<unsigned*>(dst + ((size_t)bp*65536 + (size_t)y*256)*32));
    #pragma unroll
    for (int it = 0; it < 4; ++it) {
        int v = it*256 + t;
        int x = v >> 2, cq = v & 3;
        uint4 val;
        val.x = tile32[(cq*4+0)*260 + x];
        val.y = tile32[(cq*4+1)*260 + x];
        val.z = tile32[(cq*4+2)*260 + x];
        val.w = tile32[(cq*4+3)*260 + x];
        d4[v] = val;
    }
}

// K1/K3: plane sampling + decoder MLP (MFMA). One block = 256 points.
// Descriptors live in REGISTERS and are served to gather lanes via __shfl
// (wave-local), removing 12KB of LDS -> 8 blocks/CU. Tap addresses are
// compressed to 3 u32/point: 18-bit texel base + dx/dy step bits; validity
// baked into f16 weights (6 u32 pairs). Loads use uniform-base + 32-bit
// voffset addressing.
__global__ __launch_bounds__(256, 8) void k_sample_mlp(
    const __half* __restrict__ planesT,
    const float* __restrict__ orig, const float* __restrict__ dirs,
    const unsigned* __restrict__ w1frag, const float* __restrict__ b1,
    const float* __restrict__ w2, const float* __restrict__ b2,
    const float* __restrict__ dfine,
    float* __restrict__ colors, float* __restrict__ sigmas,
    int mode)
{
    __shared__ unsigned featT[256*16];  // [pt][16 c-pairs], swizzled
    __shared__ float b1s[64];
    __shared__ float w2s[256];          // row j = w2[j][0..3]

    int tid = threadIdx.x;
    int pid = blockIdx.x * 256 + tid;
    int rid = pid / 48;
    int s   = pid - rid*48;
    int b   = rid >> 12;

    // ---- phase 0: packed tap descriptors for this thread's point ----
    float ox = orig[rid*3+0], oy = orig[rid*3+1], oz = orig[rid*3+2];
    float dxv = dirs[rid*3+0], dyv = dirs[rid*3+1], dzv = dirs[rid*3+2];
    float depth;
    if (mode == 0) {
        float cam = sqrtf(ox*ox + oy*oy + oz*oz);
        depth = coarse_depth(cam, s);
    } else {
        depth = dfine[(size_t)rid*48 + s];
    }
    float cx = ox + depth*dxv;
    float cy = oy + depth*dyv;
    float cz = oz + depth*dzv;
    float us[3] = {cx, cz, cy};   // p0 (x,y), p1 (z,x), p2 (y,z)
    float vs[3] = {cy, cx, cz};
    unsigned opk[3], wpk[6];
    #pragma unroll
    for (int pl = 0; pl < 3; ++pl) {
        float xg = (us[pl] + 1.0f) * 0.5f * 256.0f - 0.5f;
        float yg = (vs[pl] + 1.0f) * 0.5f * 256.0f - 0.5f;
        float x0f = floorf(xg), y0f = floorf(yg);
        float wx = xg - x0f, wy = yg - y0f;
        int x0 = (int)x0f, y0 = (int)y0f;
        int xc0 = min(max(x0,   0), 255), yc0 = min(max(y0,   0), 255);
        int xc1 = min(max(x0+1, 0), 255), yc1 = min(max(y0+1, 0), 255);
        bool bx0 = (x0 >= 0)  && (x0 < 256);
        bool bx1 = (x0 >= -1) && (x0 <= 254);
        bool by0 = (y0 >= 0)  && (y0 < 256);
        bool by1 = (y0 >= -1) && (y0 <= 254);
        float w00 = (bx0 && by0) ? (1.0f-wx)*(1.0f-wy) : 0.0f;
        float w10 = (bx1 && by0) ? wx*(1.0f-wy)        : 0.0f;
        float w01 = (bx0 && by1) ? (1.0f-wx)*wy        : 0.0f;
        float w11 = (bx1 && by1) ? wx*wy               : 0.0f;
        opk[pl] = (unsigned)(pl*65536 + yc0*256 + xc0)
                | ((unsigned)(xc1 - xc0) << 18)
                | ((unsigned)(yc1 - yc0) << 19);
        wpk[2*pl+0] = (unsigned)__half_as_ushort(__float2half_rn(w00))
                    | ((unsigned)__half_as_ushort(__float2half_rn(w10)) << 16);
        wpk[2*pl+1] = (unsigned)__half_as_ushort(__float2half_rn(w01))
                    | ((unsigned)__half_as_ushort(__float2half_rn(w11)) << 16);
    }
    if (tid < 64) {
        b1s[tid] = b1[tid];
        *reinterpret_cast<float4*>(&w2s[tid*4]) =
            *reinterpret_cast<const float4*>(&w2[tid*4]);
    }
    __syncthreads();   // b1s/w2s only (descriptors are register-resident)

    // ---- phase 1: per-wave gather, 8 lanes/point, 8B taps, hfma2 ----
    int lane = tid & 63, wbase = tid & 192;
    int g8 = lane >> 3, sub = lane & 7;
    unsigned c02 = (unsigned)(sub * 8);   // byte offset of this lane's 4 channels
    const char* pb = reinterpret_cast<const char*>(planesT)
                   + (size_t)(b*3) * (size_t)PLANE_ELEMS * 2;
    const __half2 inv3h = __float2half2_rn(1.0f/3.0f);
    #pragma unroll 2
    for (int it = 0; it < 8; ++it) {
        int pp   = wbase + it*8 + g8;
        int srcl = it*8 + g8;
        unsigned ov0 = __shfl(opk[0], srcl, 64);
        unsigned ov1 = __shfl(opk[1], srcl, 64);
        unsigned ov2 = __shfl(opk[2], srcl, 64);
        unsigned wv2[6];
        #pragma unroll
        for (int q = 0; q < 6; ++q) wv2[q] = __shfl(wpk[q], srcl, 64);
        unsigned ov[3] = {ov0, ov1, ov2};
        __half2 a01 = __float2half2_rn(0.0f);
        __half2 a23 = __float2half2_rn(0.0f);
        #pragma unroll
        for (int pl = 0; pl < 3; ++pl) {
            unsigned v    = ov[pl];
            unsigned base = ((v & 0x3FFFFu) << 6) + c02;
            unsigned dxb  = (v >> 12) & 64u;      // bit18 -> 64B x-step
            unsigned dyb  = (v >> 5)  & 16384u;   // bit19 -> 16KB y-step
            uint2 t0 = *reinterpret_cast<const uint2*>(pb + base);
            uint2 t1 = *reinterpret_cast<const uint2*>(pb + (base + dxb));
            uint2 t2 = *reinterpret_cast<const uint2*>(pb + (base + dyb));
            uint2 t3 = *reinterpret_cast<const uint2*>(pb + (base + dxb + dyb));
            unsigned wl = wv2[2*pl], wh = wv2[2*pl+1];
            unsigned uw00 = __builtin_amdgcn_perm(wl, wl, 0x01000100u);
            unsigned uw10 = __builtin_amdgcn_perm(wl, wl, 0x03020302u);
            unsigned uw01 = __builtin_amdgcn_perm(wh, wh, 0x01000100u);
            unsigned uw11 = __builtin_amdgcn_perm(wh, wh, 0x03020302u);
            __half2 w00h, w10h, w01h, w11h;
            __builtin_memcpy(&w00h, &uw00, 4);
            __builtin_memcpy(&w10h, &uw10, 4);
            __builtin_memcpy(&w01h, &uw01, 4);
            __builtin_memcpy(&w11h, &uw11, 4);
            __half2 v01, v23;
            __builtin_memcpy(&v01, &t0.x, 4); __builtin_memcpy(&v23, &t0.y, 4);
            a01 = __hfma2(w00h, v01, a01);    a23 = __hfma2(w00h, v23, a23);
            __builtin_memcpy(&v01, &t1.x, 4); __builtin_memcpy(&v23, &t1.y, 4);
            a01 = __hfma2(w10h, v01, a01);    a23 = __hfma2(w10h, v23, a23);
            __builtin_memcpy(&v01, &t2.x, 4); __builtin_memcpy(&v23, &t2.y, 4);
            a01 = __hfma2(w01h, v01, a01);    a23 = __hfma2(w01h, v23, a23);
            __builtin_memcpy(&v01, &t3.x, 4); __builtin_memcpy(&v23, &t3.y, 4);
            a01 = __hfma2(w11h, v01, a01);    a23 = __hfma2(w11h, v23, a23);
        }
        a01 = __hmul2(a01, inv3h);
        a23 = __hmul2(a23, inv3h);
        unsigned u01, u23;
        __builtin_memcpy(&u01, &a01, 4);
        __builtin_memcpy(&u23, &a23, 4);
        // swizzled write: c-pairs 2sub, 2sub+1 of point pp
        int basew = pp*16 + (((sub>>1) ^ (pp&3)) << 2) + ((sub&1) << 1);
        *reinterpret_cast<uint2*>(&featT[basew]) = make_uint2(u01, u23);
    }
    // wave-local LDS handoff: drain own DS writes; DS is in-order per wave
    asm volatile("s_waitcnt lgkmcnt(0)" ::: "memory");

    // ---- phase 2: MLP via MFMA f32_16x16x32_f16 ----
    int w    = tid >> 6;
    int quad = lane >> 4;
    int n    = lane & 15;
    f16x8 af[4];
    {
        const uint4* wf = reinterpret_cast<const uint4*>(w1frag);
        #pragma unroll
        for (int ht = 0; ht < 4; ++ht) {
            uint4 u = wf[ht*64 + lane];
            __builtin_memcpy(&af[ht], &u, 16);
        }
    }
    #pragma unroll
    for (int p = 0; p < 4; ++p) {
        int ptile = w*4 + p;
        int pt    = ptile*16 + n;
        uint4 bu = *reinterpret_cast<const uint4*>(
            &featT[pt*16 + ((quad ^ (pt&3)) << 2)]);
        f16x8 bf;
        __builtin_memcpy(&bf, &bu, 16);
        float o0=0.f, o1=0.f, o2=0.f, o3=0.f;
        #pragma unroll
        for (int ht = 0; ht < 4; ++ht) {
            float4 bb = *reinterpret_cast<const float4*>(&b1s[ht*16 + quad*4]);
            f32x4 acc = {bb.x, bb.y, bb.z, bb.w};   // fold b1 into MFMA C
            acc = __builtin_amdgcn_mfma_f32_16x16x32_f16(af[ht], bf, acc, 0, 0, 0);
            #pragma unroll
            for (int r = 0; r < 4; ++r) {
                float hv = softplusf(acc[r]);
                float4 wr = *reinterpret_cast<const float4*>(
                    &w2s[(ht*16 + quad*4 + r)*4]);
                o0 = fmaf(hv, wr.x, o0);
                o1 = fmaf(hv, wr.y, o1);
                o2 = fmaf(hv, wr.z, o2);
                o3 = fmaf(hv, wr.w, o3);
            }
        }
        o0 += __shfl_xor(o0, 16); o0 += __shfl_xor(o0, 32);
        o1 += __shfl_xor(o1, 16); o1 += __shfl_xor(o1, 32);
        o2 += __shfl_xor(o2, 16); o2 += __shfl_xor(o2, 32);
        o3 += __shfl_xor(o3, 16); o3 += __shfl_xor(o3, 32);
        int pid2 = blockIdx.x*256 + ptile*16 + n;
        int rid2 = pid2 / 48;
        int s2   = pid2 - rid2*48;
        int slot = rid2*96 + (mode ? 48 + s2 : s2);
        if (quad == 0) {
            sigmas[slot] = 10.0f * softplusf(-10.0f * (o0 + b2[0]));
        } else {
            float oc = (quad == 1) ? o1 : (quad == 2 ? o2 : o3);
            colors[(size_t)slot*3 + (quad-1)] =
                sigmoidf(oc + b2[quad]) * 1.002f - 0.001f;
        }
    }
}

// K2: per-ray coarse weights -> blurred pdf -> inverse-CDF fine depths.
__global__ __launch_bounds__(64) void k_importance(
    const float* __restrict__ orig, const float* __restrict__ sigmas,
    float* __restrict__ dfine)
{
    __shared__ float tile[64*49];
    int t  = threadIdx.x;
    int r0 = blockIdx.x * 64;
    for (int it = 0; it < 48; ++it) {
        int l  = it*64 + t;
        int ri = l / 48;
        int i  = l - ri*48;
        tile[ri*49 + i] = sigmas[(size_t)(r0+ri)*96 + i];
    }
    __syncthreads();
    int rid = r0 + t;
    float ox = orig[rid*3+0], oy = orig[rid*3+1], oz = orig[rid*3+2];
    float cam = sqrtf(ox*ox + oy*oy + oz*oz);

    float w[47];
    float T = 1.0f;
    float sp_ = tile[t*49 + 0];
    float dprev = coarse_depth(cam, 0);
    #pragma unroll
    for (int i = 0; i < 47; ++i) {
        float sc = tile[t*49 + i + 1];
        float dnext = coarse_depth(cam, i+1);
        float delta = dnext - dprev;
        float dm = 0.5f*(sp_ + sc);
        float a = 1.0f - __expf(-delta*dm);
        w[i] = a * T;
        T *= (1.0f - a + 1e-10f);
        sp_ = sc; dprev = dnext;
    }
    float Ssum = 0.0f;
    #pragma unroll
    for (int m = 0; m < 45; ++m) {
        float wm1 = fmaxf(w[m],   w[m+1]);
        float wm2 = fmaxf(w[m+1], w[m+2]);
        float wq = (0.5f*(wm1 + wm2) + 0.01f) + 1e-5f;
        tile[t*49 + m] = wq;
        Ssum += wq;
    }
    int idx = 1;
    float cprev = 0.0f;
    float ccur  = tile[t*49 + 0] / Ssum;
    for (int k = 0; k < 48; ++k) {
        float u = (float)k * (1.0f/47.0f);
        while (idx < 46 && ccur <= u) {
            cprev = ccur;
            idx++;
            if (idx < 46) ccur += tile[t*49 + (idx-1)] / Ssum;
        }
        int below = idx - 1;
        int above = min(idx, 45);
        float cb = cprev;
        float ca = (idx < 46) ? ccur : cprev;
        float bb = 0.5f*(coarse_depth(cam, below) + coarse_depth(cam, below+1));
        float ba = 0.5f*(coarse_depth(cam, above) + coarse_depth(cam, above+1));
        float d_ = ca - cb;
        float den = (d_ < 1e-5f) ? 1.0f : d_;
        dfine[(size_t)rid*48 + k] = bb + (u - cb)/den * (ba - bb);
    }
}

// K4: stable merge + final ray march; sample data staged coalesced into LDS.
__global__ __launch_bounds__(64) void k_final(
    const float* __restrict__ orig,
    const float* __restrict__ colors, const float* __restrict__ sigmas,
    const float* __restrict__ dfine, float* __restrict__ out)
{
    __shared__ float scol[32*289];
    __shared__ float ssig[32*97];
    __shared__ float sdf [32*49];
    int t  = threadIdx.x;
    int r0 = blockIdx.x * 32;

    {
        const float4* src = reinterpret_cast<const float4*>(colors + (size_t)r0*288);
        for (int q = t; q < 2304; q += 64) {
            float4 v = src[q];
            int e = q*4, row = e/288, col = e - row*288;
            scol[row*289+col+0] = v.x; scol[row*289+col+1] = v.y;
            scol[row*289+col+2] = v.z; scol[row*289+col+3] = v.w;
        }
    }
    {
        const float4* src = reinterpret_cast<const float4*>(sigmas + (size_t)r0*96);
        for (int q = t; q < 768; q += 64) {
            float4 v = src[q];
            int e = q*4, row = e/96, col = e - row*96;
            ssig[row*97+col+0] = v.x; ssig[row*97+col+1] = v.y;
            ssig[row*97+col+2] = v.z; ssig[row*97+col+3] = v.w;
        }
    }
    {
        const float4* src = reinterpret_cast<const float4*>(dfine + (size_t)r0*48);
        for (int q = t; q < 384; q += 64) {
            float4 v = src[q];
            int e = q*4, row = e/48, col = e - row*48;
            sdf[row*49+col+0] = v.x; sdf[row*49+col+1] = v.y;
            sdf[row*49+col+2] = v.z; sdf[row*49+col+3] = v.w;
        }
    }
    __syncthreads();
    if (t >= 32) return;

    int rid = r0 + t;
    float ox = orig[rid*3+0], oy = orig[rid*3+1], oz = orig[rid*3+2];
    float cam = sqrtf(ox*ox + oy*oy + oz*oz);
    int i = 0, j = 0;
    float T = 1.0f, rgb0=0.f, rgb1=0.f, rgb2=0.f, dep=0.f, wsum=0.f;
    float dprev=0.f, sprev=0.f, cp0=0.f, cp1=0.f, cp2=0.f;
    for (int m = 0; m < 96; ++m) {
        float dc = (i < 48) ? coarse_depth(cam, i) : 3.4e38f;
        float df = (j < 48) ? sdf[t*49 + j] : 3.4e38f;
        bool takec = dc <= df;                  // stable: coarse wins ties
        int slot = takec ? i : 48 + j;
        float dcur = takec ? dc : df;
        if (takec) ++i; else ++j;
        float sc = ssig[t*97 + slot];
        float c0 = scol[t*289 + slot*3+0];
        float c1 = scol[t*289 + slot*3+1];
        float c2 = scol[t*289 + slot*3+2];
        if (m > 0) {
            float delta = dcur - dprev;
            float dm = 0.5f*(sprev + sc);
            float zm = 0.5f*(dprev + dcur);
            float a = 1.0f - __expf(-delta*dm);
            float wgt = a * T;
            T *= (1.0f - a + 1e-10f);
            rgb0 += wgt*0.5f*(cp0 + c0);
            rgb1 += wgt*0.5f*(cp1 + c1);
            rgb2 += wgt*0.5f*(cp2 + c2);
            dep  += wgt*zm;
            wsum += wgt;
        }
        dprev = dcur; sprev = sc; cp0 = c0; cp1 = c1; cp2 = c2;
    }
    out[rid*3+0] = rgb0;
    out[rid*3+1] = rgb1;
    out[rid*3+2] = rgb2;
    out[16384*3 + rid] = dep;
    out[16384*4 + rid] = wsum;
}

extern "C" void kernel_launch(void* const* d_in, const int* in_sizes, int n_in,
                              void* d_out, int out_size, void* d_ws, size_t ws_size,
                              hipStream_t stream)
{
    const float* planes = (const float*)d_in[0];
    const float* orig   = (const float*)d_in[1];
    const float* dirs   = (const float*)d_in[2];
    const float* w1     = (const float*)d_in[3];
    const float* b1     = (const float*)d_in[4];
    const float* w2     = (const float*)d_in[5];
    const float* b2     = (const float*)d_in[6];
    float* out = (float*)d_out;

    float* ws = (float*)d_ws;
    size_t n_sig = (size_t)NB*NR*96;
    size_t n_col = n_sig*3;
    size_t n_df  = (size_t)NB*NR*48;
    float*  sig     = ws;
    float*  col     = sig + n_sig;
    float*  dfin    = col + n_col;
    __half* planesT = (__half*)(dfin + n_df);              // 8B-aligned
    unsigned* w1frag = (unsigned*)(planesT + (size_t)12*PLANE_ELEMS);

    k_transpose<<<3073, 256, 0, stream>>>(planes, planesT, w1, w1frag);
    k_sample_mlp<<<3072, 256, 0, stream>>>(planesT, orig, dirs,
                                           w1frag, b1, w2, b2, dfin, col, sig, 0);
    k_importance<<<256, 64, 0, stream>>>(orig, sig, dfin);
    k_sample_mlp<<<3072, 256, 0, stream>>>(planesT, orig, dirs,
                                           w1frag, b1, w2, b2, dfin, col, sig, 1);
    k_final<<<512, 64, 0, stream>>>(orig, col, sig, dfin, out);
}

// Round 3
// 315.530 us; speedup vs baseline: 1.1216x; 1.1216x over previous
//
#include <hip/hip_runtime.h>
#include <hip/hip_fp16.h>
#include <math.h>

#define NB 4
#define NR 4096
#define NS 48
#define PLANE_ELEMS (65536*32)   // H*W*C per (b,plane) (elements)

typedef _Float16 f16x8 __attribute__((ext_vector_type(8)));
typedef float    f32x4 __attribute__((ext_vector_type(4)));

__device__ __forceinline__ float coarse_depth(float cam, int i) {
    float nearv = cam - 0.5f;
    float farv  = cam + 0.5f;
    float t = ((float)i + 0.5f) / 48.0f;
    return nearv + (farv - nearv) * t;
}
__device__ __forceinline__ float softplusf(float x) {
    return fmaxf(x, 0.0f) + __logf(1.0f + __expf(-fabsf(x)));
}
__device__ __forceinline__ float sigmoidf(float x) {
    return 1.0f / (1.0f + __expf(-x));
}

// K0: transpose planes [bp][C][H][W] f32 -> [bp][H][W][C] f16 (64B/texel).
// Block 3072 packs w1 into MFMA A-fragment layout (unchanged).
__global__ __launch_bounds__(256) void k_transpose(const float* __restrict__ src,
                                                   __half* __restrict__ dst,
                                                   const float* __restrict__ w1,
                                                   unsigned* __restrict__ w1frag) {
    if (blockIdx.x == 3072) {
        int t = threadIdx.x;
        for (int f = t; f < 1024; f += 256) {
            int ht = f >> 8, rem = f & 255, lane = rem >> 2, qq = rem & 3;
            int quad = lane >> 4, m = lane & 15;
            int k0 = quad*8 + 2*qq;
            __half lo = __float2half_rn(w1[(k0+0)*64 + ht*16 + m]);
            __half hi = __float2half_rn(w1[(k0+1)*64 + ht*16 + m]);
            w1frag[f] = (unsigned)__half_as_ushort(lo)
                      | ((unsigned)__half_as_ushort(hi) << 16);
        }
        return;
    }
    // tile32[cp][x]: packed u32 = half(c=2cp,x) | half(c=2cp+1,x)<<16
    __shared__ unsigned tile32[16*260];
    int bp = blockIdx.x >> 8;
    int y  = blockIdx.x & 255;
    int t  = threadIdx.x;
    const float4* s4 = reinterpret_cast<const float4*>(
        src + (size_t)bp*PLANE_ELEMS + (size_t)y*256);
    #pragma unroll
    for (int it = 0; it < 4; ++it) {
        int idx = it*256 + t;
        int cp = idx >> 6, x4 = idx & 63;          // cp uniform per wave
        float4 a = s4[(size_t)(2*cp)*16384 + x4];  // channel 2cp, 4 pixels
        float4 b = s4[(size_t)(2*cp+1)*16384 + x4];
        unsigned u0 = (unsigned)__half_as_ushort(__float2half_rn(a.x))
                    | ((unsigned)__half_as_ushort(__float2half_rn(b.x)) << 16);
        unsigned u1 = (unsigned)__half_as_ushort(__float2half_rn(a.y))
                    | ((unsigned)__half_as_ushort(__float2half_rn(b.y)) << 16);
        unsigned u2 = (unsigned)__half_as_ushort(__float2half_rn(a.z))
                    | ((unsigned)__half_as_ushort(__float2half_rn(b.z)) << 16);
        unsigned u3 = (unsigned)__half_as_ushort(__float2half_rn(a.w))
                    | ((unsigned)__half_as_ushort(__float2half_rn(b.w)) << 16);
        *reinterpret_cast<uint4*>(&tile32[cp*260 + x4*4]) = make_uint4(u0,u1,u2,u3);
    }
    __syncthreads();
    uint4* d4 = reinterpret_cast<uint4*>(
        reinterpret_cast<unsigned*>(dst + ((size_t)bp*65536 + (size_t)y*256)*32));
    #pragma unroll
    for (int it = 0; it < 4; ++it) {
        int v = it*256 + t;
        int x = v >> 2, cq = v & 3;
        uint4 val;
        val.x = tile32[(cq*4+0)*260 + x];
        val.y = tile32[(cq*4+1)*260 + x];
        val.z = tile32[(cq*4+2)*260 + x];
        val.w = tile32[(cq*4+3)*260 + x];
        d4[v] = val;
    }
}

// K1/K3: plane sampling + decoder MLP (MFMA). One block = 256 points.
// (unchanged from previous round)
__global__ __launch_bounds__(256, 8) void k_sample_mlp(
    const __half* __restrict__ planesT,
    const float* __restrict__ orig, const float* __restrict__ dirs,
    const unsigned* __restrict__ w1frag, const float* __restrict__ b1,
    const float* __restrict__ w2, const float* __restrict__ b2,
    const float* __restrict__ dfine,
    float* __restrict__ colors, float* __restrict__ sigmas,
    int mode)
{
    __shared__ unsigned featT[256*16];  // [pt][16 c-pairs], swizzled
    __shared__ float b1s[64];
    __shared__ float w2s[256];          // row j = w2[j][0..3]

    int tid = threadIdx.x;
    int pid = blockIdx.x * 256 + tid;
    int rid = pid / 48;
    int s   = pid - rid*48;
    int b   = rid >> 12;

    // ---- phase 0: packed tap descriptors for this thread's point ----
    float ox = orig[rid*3+0], oy = orig[rid*3+1], oz = orig[rid*3+2];
    float dxv = dirs[rid*3+0], dyv = dirs[rid*3+1], dzv = dirs[rid*3+2];
    float depth;
    if (mode == 0) {
        float cam = sqrtf(ox*ox + oy*oy + oz*oz);
        depth = coarse_depth(cam, s);
    } else {
        depth = dfine[(size_t)rid*48 + s];
    }
    float cx = ox + depth*dxv;
    float cy = oy + depth*dyv;
    float cz = oz + depth*dzv;
    float us[3] = {cx, cz, cy};   // p0 (x,y), p1 (z,x), p2 (y,z)
    float vs[3] = {cy, cx, cz};
    unsigned opk[3], wpk[6];
    #pragma unroll
    for (int pl = 0; pl < 3; ++pl) {
        float xg = (us[pl] + 1.0f) * 0.5f * 256.0f - 0.5f;
        float yg = (vs[pl] + 1.0f) * 0.5f * 256.0f - 0.5f;
        float x0f = floorf(xg), y0f = floorf(yg);
        float wx = xg - x0f, wy = yg - y0f;
        int x0 = (int)x0f, y0 = (int)y0f;
        int xc0 = min(max(x0,   0), 255), yc0 = min(max(y0,   0), 255);
        int xc1 = min(max(x0+1, 0), 255), yc1 = min(max(y0+1, 0), 255);
        bool bx0 = (x0 >= 0)  && (x0 < 256);
        bool bx1 = (x0 >= -1) && (x0 <= 254);
        bool by0 = (y0 >= 0)  && (y0 < 256);
        bool by1 = (y0 >= -1) && (y0 <= 254);
        float w00 = (bx0 && by0) ? (1.0f-wx)*(1.0f-wy) : 0.0f;
        float w10 = (bx1 && by0) ? wx*(1.0f-wy)        : 0.0f;
        float w01 = (bx0 && by1) ? (1.0f-wx)*wy        : 0.0f;
        float w11 = (bx1 && by1) ? wx*wy               : 0.0f;
        opk[pl] = (unsigned)(pl*65536 + yc0*256 + xc0)
                | ((unsigned)(xc1 - xc0) << 18)
                | ((unsigned)(yc1 - yc0) << 19);
        wpk[2*pl+0] = (unsigned)__half_as_ushort(__float2half_rn(w00))
                    | ((unsigned)__half_as_ushort(__float2half_rn(w10)) << 16);
        wpk[2*pl+1] = (unsigned)__half_as_ushort(__float2half_rn(w01))
                    | ((unsigned)__half_as_ushort(__float2half_rn(w11)) << 16);
    }
    if (tid < 64) {
        b1s[tid] = b1[tid];
        *reinterpret_cast<float4*>(&w2s[tid*4]) =
            *reinterpret_cast<const float4*>(&w2[tid*4]);
    }
    __syncthreads();   // b1s/w2s only (descriptors are register-resident)

    // ---- phase 1: per-wave gather, 8 lanes/point, 8B taps, hfma2 ----
    int lane = tid & 63, wbase = tid & 192;
    int g8 = lane >> 3, sub = lane & 7;
    unsigned c02 = (unsigned)(sub * 8);   // byte offset of this lane's 4 channels
    const char* pb = reinterpret_cast<const char*>(planesT)
                   + (size_t)(b*3) * (size_t)PLANE_ELEMS * 2;
    const __half2 inv3h = __float2half2_rn(1.0f/3.0f);
    #pragma unroll 2
    for (int it = 0; it < 8; ++it) {
        int pp   = wbase + it*8 + g8;
        int srcl = it*8 + g8;
        unsigned ov0 = __shfl(opk[0], srcl, 64);
        unsigned ov1 = __shfl(opk[1], srcl, 64);
        unsigned ov2 = __shfl(opk[2], srcl, 64);
        unsigned wv2[6];
        #pragma unroll
        for (int q = 0; q < 6; ++q) wv2[q] = __shfl(wpk[q], srcl, 64);
        unsigned ov[3] = {ov0, ov1, ov2};
        __half2 a01 = __float2half2_rn(0.0f);
        __half2 a23 = __float2half2_rn(0.0f);
        #pragma unroll
        for (int pl = 0; pl < 3; ++pl) {
            unsigned v    = ov[pl];
            unsigned base = ((v & 0x3FFFFu) << 6) + c02;
            unsigned dxb  = (v >> 12) & 64u;      // bit18 -> 64B x-step
            unsigned dyb  = (v >> 5)  & 16384u;   // bit19 -> 16KB y-step
            uint2 t0 = *reinterpret_cast<const uint2*>(pb + base);
            uint2 t1 = *reinterpret_cast<const uint2*>(pb + (base + dxb));
            uint2 t2 = *reinterpret_cast<const uint2*>(pb + (base + dyb));
            uint2 t3 = *reinterpret_cast<const uint2*>(pb + (base + dxb + dyb));
            unsigned wl = wv2[2*pl], wh = wv2[2*pl+1];
            unsigned uw00 = __builtin_amdgcn_perm(wl, wl, 0x01000100u);
            unsigned uw10 = __builtin_amdgcn_perm(wl, wl, 0x03020302u);
            unsigned uw01 = __builtin_amdgcn_perm(wh, wh, 0x01000100u);
            unsigned uw11 = __builtin_amdgcn_perm(wh, wh, 0x03020302u);
            __half2 w00h, w10h, w01h, w11h;
            __builtin_memcpy(&w00h, &uw00, 4);
            __builtin_memcpy(&w10h, &uw10, 4);
            __builtin_memcpy(&w01h, &uw01, 4);
            __builtin_memcpy(&w11h, &uw11, 4);
            __half2 v01, v23;
            __builtin_memcpy(&v01, &t0.x, 4); __builtin_memcpy(&v23, &t0.y, 4);
            a01 = __hfma2(w00h, v01, a01);    a23 = __hfma2(w00h, v23, a23);
            __builtin_memcpy(&v01, &t1.x, 4); __builtin_memcpy(&v23, &t1.y, 4);
            a01 = __hfma2(w10h, v01, a01);    a23 = __hfma2(w10h, v23, a23);
            __builtin_memcpy(&v01, &t2.x, 4); __builtin_memcpy(&v23, &t2.y, 4);
            a01 = __hfma2(w01h, v01, a01);    a23 = __hfma2(w01h, v23, a23);
            __builtin_memcpy(&v01, &t3.x, 4); __builtin_memcpy(&v23, &t3.y, 4);
            a01 = __hfma2(w11h, v01, a01);    a23 = __hfma2(w11h, v23, a23);
        }
        a01 = __hmul2(a01, inv3h);
        a23 = __hmul2(a23, inv3h);
        unsigned u01, u23;
        __builtin_memcpy(&u01, &a01, 4);
        __builtin_memcpy(&u23, &a23, 4);
        // swizzled write: c-pairs 2sub, 2sub+1 of point pp
        int basew = pp*16 + (((sub>>1) ^ (pp&3)) << 2) + ((sub&1) << 1);
        *reinterpret_cast<uint2*>(&featT[basew]) = make_uint2(u01, u23);
    }
    // wave-local LDS handoff: drain own DS writes; DS is in-order per wave
    asm volatile("s_waitcnt lgkmcnt(0)" ::: "memory");

    // ---- phase 2: MLP via MFMA f32_16x16x32_f16 ----
    int w    = tid >> 6;
    int quad = lane >> 4;
    int n    = lane & 15;
    f16x8 af[4];
    {
        const uint4* wf = reinterpret_cast<const uint4*>(w1frag);
        #pragma unroll
        for (int ht = 0; ht < 4; ++ht) {
            uint4 u = wf[ht*64 + lane];
            __builtin_memcpy(&af[ht], &u, 16);
        }
    }
    #pragma unroll
    for (int p = 0; p < 4; ++p) {
        int ptile = w*4 + p;
        int pt    = ptile*16 + n;
        uint4 bu = *reinterpret_cast<const uint4*>(
            &featT[pt*16 + ((quad ^ (pt&3)) << 2)]);
        f16x8 bf;
        __builtin_memcpy(&bf, &bu, 16);
        float o0=0.f, o1=0.f, o2=0.f, o3=0.f;
        #pragma unroll
        for (int ht = 0; ht < 4; ++ht) {
            float4 bb = *reinterpret_cast<const float4*>(&b1s[ht*16 + quad*4]);
            f32x4 acc = {bb.x, bb.y, bb.z, bb.w};   // fold b1 into MFMA C
            acc = __builtin_amdgcn_mfma_f32_16x16x32_f16(af[ht], bf, acc, 0, 0, 0);
            #pragma unroll
            for (int r = 0; r < 4; ++r) {
                float hv = softplusf(acc[r]);
                float4 wr = *reinterpret_cast<const float4*>(
                    &w2s[(ht*16 + quad*4 + r)*4]);
                o0 = fmaf(hv, wr.x, o0);
                o1 = fmaf(hv, wr.y, o1);
                o2 = fmaf(hv, wr.z, o2);
                o3 = fmaf(hv, wr.w, o3);
            }
        }
        o0 += __shfl_xor(o0, 16); o0 += __shfl_xor(o0, 32);
        o1 += __shfl_xor(o1, 16); o1 += __shfl_xor(o1, 32);
        o2 += __shfl_xor(o2, 16); o2 += __shfl_xor(o2, 32);
        o3 += __shfl_xor(o3, 16); o3 += __shfl_xor(o3, 32);
        int pid2 = blockIdx.x*256 + ptile*16 + n;
        int rid2 = pid2 / 48;
        int s2   = pid2 - rid2*48;
        int slot = rid2*96 + (mode ? 48 + s2 : s2);
        if (quad == 0) {
            sigmas[slot] = 10.0f * softplusf(-10.0f * (o0 + b2[0]));
        } else {
            float oc = (quad == 1) ? o1 : (quad == 2 ? o2 : o3);
            colors[(size_t)slot*3 + (quad-1)] =
                sigmoidf(oc + b2[quad]) * 1.002f - 0.001f;
        }
    }
}

// K2: importance sampling, ONE WAVE PER RAY, fully parallel.
// Lanes 0..47 hold samples; shuffle scans for cumprod/cumsum; per-lane
// binary search over lane-resident CDF for the inverse transform.
__global__ __launch_bounds__(256) void k_importance(
    const float* __restrict__ orig, const float* __restrict__ sigmas,
    float* __restrict__ dfine)
{
    int t    = threadIdx.x;
    int lane = t & 63;
    int rid  = blockIdx.x * 4 + (t >> 6);

    float sig = 0.0f;
    if (lane < 48) sig = sigmas[(size_t)rid*96 + lane];
    float ox = orig[rid*3+0], oy = orig[rid*3+1], oz = orig[rid*3+2];
    float cam = sqrtf(ox*ox + oy*oy + oz*oz);

    // alpha_i on lanes i = 0..46
    float sig1  = __shfl(sig, lane + 1, 64);
    float dprev = coarse_depth(cam, lane);
    float dnext = coarse_depth(cam, lane + 1);
    float a = 0.0f;
    if (lane < 47) {
        float delta = dnext - dprev;
        float dm = 0.5f*(sig + sig1);
        a = 1.0f - __expf(-delta*dm);
    }
    float v = 1.0f - a + 1e-10f;          // lanes >=47: a=0 (harmless above)
    // inclusive product scan (Kogge-Stone)
    float p = v;
    #pragma unroll
    for (int off = 1; off < 64; off <<= 1) {
        float q = __shfl_up(p, off, 64);
        if (lane >= off) p *= q;
    }
    float T = __shfl_up(p, 1, 64);
    if (lane == 0) T = 1.0f;
    float w = a * T;                      // w_i; exact 0 for lanes >= 47
    // blurred pdf: wm_j = max(w_{j-1}, w_j); pdf_p = 0.5*(wm_{p+1}+wm_{p+2})+0.01+1e-5
    float wprev = __shfl_up(w, 1, 64);
    if (lane == 0) wprev = 0.0f;
    float wm  = fmaxf(wprev, w);          // valid j = 0..47
    float wm1 = __shfl(wm, lane + 1, 64);
    float wm2 = __shfl(wm, lane + 2, 64);
    float pdf = 0.0f;
    if (lane < 45) pdf = 0.5f*(wm1 + wm2) + 0.01f + 1e-5f;
    // inclusive sum scan
    float c = pdf;
    #pragma unroll
    for (int off = 1; off < 64; off <<= 1) {
        float q = __shfl_up(c, off, 64);
        if (lane >= off) c += q;
    }
    float S = __shfl(c, 44, 64);
    // cdf_full[j] on lane j: 0 for j=0, csum_{j-1}/S for j>=1 (lane46 -> 1.0)
    float cdfF = __shfl_up(c, 1, 64) / S;
    if (lane == 0) cdfF = 0.0f;

    float u = (float)lane * (1.0f/47.0f);
    int lo = 1, hi = 46;
    #pragma unroll
    for (int stp = 0; stp < 6; ++stp) {
        int mid = (lo + hi) >> 1;
        float cm = __shfl(cdfF, mid, 64);
        if (lo < hi) { if (cm > u) hi = mid; else lo = mid + 1; }
    }
    int ind   = lo;
    int below = ind - 1;
    int above = min(ind, 45);
    float cb = __shfl(cdfF, below, 64);
    float ca = __shfl(cdfF, above, 64);
    float bb = 0.5f*(coarse_depth(cam, below) + coarse_depth(cam, below+1));
    float ba = 0.5f*(coarse_depth(cam, above) + coarse_depth(cam, above+1));
    float d_  = ca - cb;
    float den = (d_ < 1e-5f) ? 1.0f : d_;
    if (lane < 48)
        dfine[(size_t)rid*48 + lane] = bb + (u - cb)/den * (ba - bb);
}

__device__ __forceinline__ int lb_sdf(const float* sdf, float key) {
    // count of sdf[j] < key, j in [0,48)
    int lo = 0, hi = 48;
    #pragma unroll
    for (int i = 0; i < 6; ++i) {
        int mid = (lo + hi) >> 1;
        float sv = sdf[mid];
        if (lo < hi) { if (sv < key) lo = mid + 1; else hi = mid; }
    }
    return lo;
}
__device__ __forceinline__ int ub_dc(const float* dc, float key) {
    // count of dc[i] <= key, i in [0,48)
    int lo = 0, hi = 48;
    #pragma unroll
    for (int i = 0; i < 6; ++i) {
        int mid = (lo + hi) >> 1;
        float dv = dc[mid];
        if (lo < hi) { if (dv <= key) lo = mid + 1; else hi = mid; }
    }
    return lo;
}

// K4: final merge + ray march, ONE WAVE PER RAY.
// Stable merge via rank computation (complementary predicates on the SAME
// LDS-stored floats guarantee a collision-free permutation, coarse wins
// ties), scatter to per-warp LDS, then parallel transmittance scan +
// butterfly reductions. No __syncthreads (wave-local LDS only).
__global__ __launch_bounds__(256) void k_final(
    const float* __restrict__ orig,
    const float* __restrict__ colors, const float* __restrict__ sigmas,
    const float* __restrict__ dfine, float* __restrict__ out)
{
    __shared__ float lds[4][48 + 48 + 5*96 + 8];
    int t    = threadIdx.x;
    int lane = t & 63;
    int wv   = t >> 6;
    int rid  = blockIdx.x * 4 + wv;
    float* sdf = &lds[wv][0];
    float* dcl = &lds[wv][48];
    float* md  = &lds[wv][96];
    float* ms  = &lds[wv][96 + 96];
    float* mc0 = &lds[wv][96 + 2*96];
    float* mc1 = &lds[wv][96 + 3*96];
    float* mc2 = &lds[wv][96 + 4*96];

    float ox = orig[rid*3+0], oy = orig[rid*3+1], oz = orig[rid*3+2];
    float cam = sqrtf(ox*ox + oy*oy + oz*oz);

    if (lane < 48) {
        sdf[lane] = dfine[(size_t)rid*48 + lane];
        dcl[lane] = coarse_depth(cam, lane);
    }
    asm volatile("s_waitcnt lgkmcnt(0)" ::: "memory");

    // ---- scatter source samples to merged order ----
    {   // source 0: s = lane (0..47 coarse, 48..63 fine j=0..15)
        int s = lane;
        float sg = sigmas[(size_t)rid*96 + s];
        float q0 = colors[((size_t)rid*96 + s)*3 + 0];
        float q1 = colors[((size_t)rid*96 + s)*3 + 1];
        float q2 = colors[((size_t)rid*96 + s)*3 + 2];
        float dsv; int r;
        if (s < 48) {
            dsv = dcl[s];
            r = s + lb_sdf(sdf, dsv);
        } else {
            int j = s - 48;
            dsv = sdf[j];
            r = j + ub_dc(dcl, dsv);
        }
        md [r] = dsv; ms [r] = sg;
        mc0[r] = q0;  mc1[r] = q1;  mc2[r] = q2;
    }
    if (lane < 32) {  // source 1: s = lane+64 (fine j = lane+16)
        int j = lane + 16;
        int s = j + 48;
        float sg = sigmas[(size_t)rid*96 + s];
        float q0 = colors[((size_t)rid*96 + s)*3 + 0];
        float q1 = colors[((size_t)rid*96 + s)*3 + 1];
        float q2 = colors[((size_t)rid*96 + s)*3 + 2];
        float dsv = sdf[j];
        int r = j + ub_dc(dcl, dsv);
        md [r] = dsv; ms [r] = sg;
        mc0[r] = q0;  mc1[r] = q1;  mc2[r] = q2;
    }
    asm volatile("s_waitcnt lgkmcnt(0)" ::: "memory");

    // ---- intervals: segment A p=lane (m=lane+1), segment B p=64+lane ----
    float aA, vA, cA0, cA1, cA2, zA;
    {
        int m = lane + 1;
        float d0 = md[m-1], d1 = md[m];
        float s0 = ms[m-1], s1 = ms[m];
        aA = 1.0f - __expf(-(d1 - d0) * 0.5f*(s0 + s1));
        vA = 1.0f - aA + 1e-10f;
        cA0 = 0.5f*(mc0[m-1] + mc0[m]);
        cA1 = 0.5f*(mc1[m-1] + mc1[m]);
        cA2 = 0.5f*(mc2[m-1] + mc2[m]);
        zA  = 0.5f*(d0 + d1);
    }
    float aB = 0.0f, vB = 1.0f, cB0 = 0.0f, cB1 = 0.0f, cB2 = 0.0f, zB = 0.0f;
    if (lane < 31) {
        int m = lane + 65;
        float d0 = md[m-1], d1 = md[m];
        float s0 = ms[m-1], s1 = ms[m];
        aB = 1.0f - __expf(-(d1 - d0) * 0.5f*(s0 + s1));
        vB = 1.0f - aB + 1e-10f;
        cB0 = 0.5f*(mc0[m-1] + mc0[m]);
        cB1 = 0.5f*(mc1[m-1] + mc1[m]);
        cB2 = 0.5f*(mc2[m-1] + mc2[m]);
        zB  = 0.5f*(d0 + d1);
    }
    // product scans
    float pA = vA;
    #pragma unroll
    for (int off = 1; off < 64; off <<= 1) {
        float q = __shfl_up(pA, off, 64);
        if (lane >= off) pA *= q;
    }
    float TA = __shfl_up(pA, 1, 64);
    if (lane == 0) TA = 1.0f;
    float totA = __shfl(pA, 63, 64);
    float pB = vB;
    #pragma unroll
    for (int off = 1; off < 64; off <<= 1) {
        float q = __shfl_up(pB, off, 64);
        if (lane >= off) pB *= q;
    }
    float TB = __shfl_up(pB, 1, 64);
    if (lane == 0) TB = 1.0f;
    TB *= totA;

    float wA = aA * TA;
    float wB = aB * TB;                    // lanes >= 31: aB = 0
    float r0 = wA*cA0 + wB*cB0;
    float r1 = wA*cA1 + wB*cB1;
    float r2 = wA*cA2 + wB*cB2;
    float rd = wA*zA  + wB*zB;
    float rw = wA + wB;
    #pragma unroll
    for (int off = 1; off < 64; off <<= 1) {
        r0 += __shfl_xor(r0, off);
        r1 += __shfl_xor(r1, off);
        r2 += __shfl_xor(r2, off);
        rd += __shfl_xor(rd, off);
        rw += __shfl_xor(rw, off);
    }
    if (lane == 0) {
        out[rid*3+0] = r0;
        out[rid*3+1] = r1;
        out[rid*3+2] = r2;
        out[16384*3 + rid] = rd;
        out[16384*4 + rid] = rw;
    }
}

extern "C" void kernel_launch(void* const* d_in, const int* in_sizes, int n_in,
                              void* d_out, int out_size, void* d_ws, size_t ws_size,
                              hipStream_t stream)
{
    const float* planes = (const float*)d_in[0];
    const float* orig   = (const float*)d_in[1];
    const float* dirs   = (const float*)d_in[2];
    const float* w1     = (const float*)d_in[3];
    const float* b1     = (const float*)d_in[4];
    const float* w2     = (const float*)d_in[5];
    const float* b2     = (const float*)d_in[6];
    float* out = (float*)d_out;

    float* ws = (float*)d_ws;
    size_t n_sig = (size_t)NB*NR*96;
    size_t n_col = n_sig*3;
    size_t n_df  = (size_t)NB*NR*48;
    float*  sig     = ws;
    float*  col     = sig + n_sig;
    float*  dfin    = col + n_col;
    __half* planesT = (__half*)(dfin + n_df);              // 8B-aligned
    unsigned* w1frag = (unsigned*)(planesT + (size_t)12*PLANE_ELEMS);

    k_transpose<<<3073, 256, 0, stream>>>(planes, planesT, w1, w1frag);
    k_sample_mlp<<<3072, 256, 0, stream>>>(planesT, orig, dirs,
                                           w1frag, b1, w2, b2, dfin, col, sig, 0);
    k_importance<<<4096, 256, 0, stream>>>(orig, sig, dfin);
    k_sample_mlp<<<3072, 256, 0, stream>>>(planesT, orig, dirs,
                                           w1frag, b1, w2, b2, dfin, col, sig, 1);
    k_final<<<4096, 256, 0, stream>>>(orig, col, sig, dfin, out);
}

// Round 4
// 297.308 us; speedup vs baseline: 1.1904x; 1.0613x over previous
//
#include <hip/hip_runtime.h>
#include <hip/hip_fp16.h>
#include <math.h>

#define NB 4
#define NR 4096
#define NS 48
#define PLANE_ELEMS (65536*32)   // H*W*C per (b,plane) (elements)

typedef _Float16 f16x8 __attribute__((ext_vector_type(8)));
typedef float    f32x4 __attribute__((ext_vector_type(4)));

__device__ __forceinline__ float coarse_depth(float cam, int i) {
    float nearv = cam - 0.5f;
    float farv  = cam + 0.5f;
    float t = ((float)i + 0.5f) / 48.0f;
    return nearv + (farv - nearv) * t;
}
__device__ __forceinline__ float softplusf(float x) {
    return fmaxf(x, 0.0f) + __logf(1.0f + __expf(-fabsf(x)));
}
__device__ __forceinline__ float sigmoidf(float x) {
    return 1.0f / (1.0f + __expf(-x));
}

// K0: transpose planes [bp][C][H][W] f32 -> [bp][H][W][C] f16 (64B/texel).
// Block 3072 packs w1 into MFMA A-fragment layout (unchanged).
__global__ __launch_bounds__(256) void k_transpose(const float* __restrict__ src,
                                                   __half* __restrict__ dst,
                                                   const float* __restrict__ w1,
                                                   unsigned* __restrict__ w1frag) {
    if (blockIdx.x == 3072) {
        int t = threadIdx.x;
        for (int f = t; f < 1024; f += 256) {
            int ht = f >> 8, rem = f & 255, lane = rem >> 2, qq = rem & 3;
            int quad = lane >> 4, m = lane & 15;
            int k0 = quad*8 + 2*qq;
            __half lo = __float2half_rn(w1[(k0+0)*64 + ht*16 + m]);
            __half hi = __float2half_rn(w1[(k0+1)*64 + ht*16 + m]);
            w1frag[f] = (unsigned)__half_as_ushort(lo)
                      | ((unsigned)__half_as_ushort(hi) << 16);
        }
        return;
    }
    // tile32[cp][x]: packed u32 = half(c=2cp,x) | half(c=2cp+1,x)<<16
    __shared__ unsigned tile32[16*260];
    int bp = blockIdx.x >> 8;
    int y  = blockIdx.x & 255;
    int t  = threadIdx.x;
    const float4* s4 = reinterpret_cast<const float4*>(
        src + (size_t)bp*PLANE_ELEMS + (size_t)y*256);
    #pragma unroll
    for (int it = 0; it < 4; ++it) {
        int idx = it*256 + t;
        int cp = idx >> 6, x4 = idx & 63;          // cp uniform per wave
        float4 a = s4[(size_t)(2*cp)*16384 + x4];  // channel 2cp, 4 pixels
        float4 b = s4[(size_t)(2*cp+1)*16384 + x4];
        unsigned u0 = (unsigned)__half_as_ushort(__float2half_rn(a.x))
                    | ((unsigned)__half_as_ushort(__float2half_rn(b.x)) << 16);
        unsigned u1 = (unsigned)__half_as_ushort(__float2half_rn(a.y))
                    | ((unsigned)__half_as_ushort(__float2half_rn(b.y)) << 16);
        unsigned u2 = (unsigned)__half_as_ushort(__float2half_rn(a.z))
                    | ((unsigned)__half_as_ushort(__float2half_rn(b.z)) << 16);
        unsigned u3 = (unsigned)__half_as_ushort(__float2half_rn(a.w))
                    | ((unsigned)__half_as_ushort(__float2half_rn(b.w)) << 16);
        *reinterpret_cast<uint4*>(&tile32[cp*260 + x4*4]) = make_uint4(u0,u1,u2,u3);
    }
    __syncthreads();
    uint4* d4 = reinterpret_cast<uint4*>(
        reinterpret_cast<unsigned*>(dst + ((size_t)bp*65536 + (size_t)y*256)*32));
    #pragma unroll
    for (int it = 0; it < 4; ++it) {
        int v = it*256 + t;
        int x = v >> 2, cq = v & 3;
        uint4 val;
        val.x = tile32[(cq*4+0)*260 + x];
        val.y = tile32[(cq*4+1)*260 + x];
        val.z = tile32[(cq*4+2)*260 + x];
        val.w = tile32[(cq*4+3)*260 + x];
        d4[v] = val;
    }
}

// K1/K3: plane sampling + decoder MLP (MFMA). One block = 256 points.
// Gather restructured to 16B dwordx4 loads: lane&3 = channel chunk,
// lane&4 = x-tap; instr A = y0 row taps, instr B = +dy. Halves VMEM
// instruction count (96->48/thread) and per-texel request count (8->4).
// shfl_xor(4) folds the two tap-halves; lanes sub<4 write the finished
// 16B chunk to featT with the same swizzle phase 2 reads.
__global__ __launch_bounds__(256, 8) void k_sample_mlp(
    const __half* __restrict__ planesT,
    const float* __restrict__ orig, const float* __restrict__ dirs,
    const unsigned* __restrict__ w1frag, const float* __restrict__ b1,
    const float* __restrict__ w2, const float* __restrict__ b2,
    const float* __restrict__ dfine,
    float* __restrict__ colors, float* __restrict__ sigmas,
    int mode)
{
    __shared__ unsigned featT[256*16];  // [pt][16 c-pairs], swizzled
    __shared__ float b1s[64];
    __shared__ float w2s[256];          // row j = w2[j][0..3]

    int tid = threadIdx.x;
    int pid = blockIdx.x * 256 + tid;
    int rid = pid / 48;
    int s   = pid - rid*48;
    int b   = rid >> 12;

    // ---- phase 0: packed tap descriptors for this thread's point ----
    float ox = orig[rid*3+0], oy = orig[rid*3+1], oz = orig[rid*3+2];
    float dxv = dirs[rid*3+0], dyv = dirs[rid*3+1], dzv = dirs[rid*3+2];
    float depth;
    if (mode == 0) {
        float cam = sqrtf(ox*ox + oy*oy + oz*oz);
        depth = coarse_depth(cam, s);
    } else {
        depth = dfine[(size_t)rid*48 + s];
    }
    float cx = ox + depth*dxv;
    float cy = oy + depth*dyv;
    float cz = oz + depth*dzv;
    float us[3] = {cx, cz, cy};   // p0 (x,y), p1 (z,x), p2 (y,z)
    float vs[3] = {cy, cx, cz};
    unsigned opk[3], wpk[6];
    #pragma unroll
    for (int pl = 0; pl < 3; ++pl) {
        float xg = (us[pl] + 1.0f) * 0.5f * 256.0f - 0.5f;
        float yg = (vs[pl] + 1.0f) * 0.5f * 256.0f - 0.5f;
        float x0f = floorf(xg), y0f = floorf(yg);
        float wx = xg - x0f, wy = yg - y0f;
        int x0 = (int)x0f, y0 = (int)y0f;
        int xc0 = min(max(x0,   0), 255), yc0 = min(max(y0,   0), 255);
        int xc1 = min(max(x0+1, 0), 255), yc1 = min(max(y0+1, 0), 255);
        bool bx0 = (x0 >= 0)  && (x0 < 256);
        bool bx1 = (x0 >= -1) && (x0 <= 254);
        bool by0 = (y0 >= 0)  && (y0 < 256);
        bool by1 = (y0 >= -1) && (y0 <= 254);
        float w00 = (bx0 && by0) ? (1.0f-wx)*(1.0f-wy) : 0.0f;
        float w10 = (bx1 && by0) ? wx*(1.0f-wy)        : 0.0f;
        float w01 = (bx0 && by1) ? (1.0f-wx)*wy        : 0.0f;
        float w11 = (bx1 && by1) ? wx*wy               : 0.0f;
        opk[pl] = (unsigned)(pl*65536 + yc0*256 + xc0)
                | ((unsigned)(xc1 - xc0) << 18)
                | ((unsigned)(yc1 - yc0) << 19);
        wpk[2*pl+0] = (unsigned)__half_as_ushort(__float2half_rn(w00))
                    | ((unsigned)__half_as_ushort(__float2half_rn(w10)) << 16);
        wpk[2*pl+1] = (unsigned)__half_as_ushort(__float2half_rn(w01))
                    | ((unsigned)__half_as_ushort(__float2half_rn(w11)) << 16);
    }
    if (tid < 64) {
        b1s[tid] = b1[tid];
        *reinterpret_cast<float4*>(&w2s[tid*4]) =
            *reinterpret_cast<const float4*>(&w2[tid*4]);
    }
    __syncthreads();   // b1s/w2s only (descriptors are register-resident)

    // ---- phase 1: per-wave gather, 8 lanes/point, 16B taps ----
    int lane = tid & 63, wbase = tid & 192;
    int g8 = lane >> 3;
    int chunk = lane & 3;                 // 16B chunk of the 64B texel
    unsigned chunkoff = (unsigned)(chunk * 16);
    unsigned selA = (lane & 4) ? 0x03020302u : 0x01000100u;  // hi/lo half2 bcast
    const char* pb = reinterpret_cast<const char*>(planesT)
                   + (size_t)(b*3) * (size_t)PLANE_ELEMS * 2;
    const __half2 inv3h = __float2half2_rn(1.0f/3.0f);
    #pragma unroll 2
    for (int it = 0; it < 8; ++it) {
        int pp   = wbase + it*8 + g8;
        int srcl = it*8 + g8;
        unsigned ov0 = __shfl(opk[0], srcl, 64);
        unsigned ov1 = __shfl(opk[1], srcl, 64);
        unsigned ov2 = __shfl(opk[2], srcl, 64);
        unsigned wv2[6];
        #pragma unroll
        for (int q = 0; q < 6; ++q) wv2[q] = __shfl(wpk[q], srcl, 64);
        unsigned ov[3] = {ov0, ov1, ov2};
        __half2 acc0 = __float2half2_rn(0.0f);
        __half2 acc1 = __float2half2_rn(0.0f);
        __half2 acc2 = __float2half2_rn(0.0f);
        __half2 acc3 = __float2half2_rn(0.0f);
        #pragma unroll
        for (int pl = 0; pl < 3; ++pl) {
            unsigned v    = ov[pl];
            unsigned dxb  = (lane & 4) ? ((v >> 12) & 64u) : 0u;  // 64B x-step
            unsigned dyb  = (v >> 5)  & 16384u;                   // 16KB y-step
            unsigned base = ((v & 0x3FFFFu) << 6) + chunkoff + dxb;
            uint4 tA = *reinterpret_cast<const uint4*>(pb + base);
            uint4 tB = *reinterpret_cast<const uint4*>(pb + (base + dyb));
            unsigned uwA = __builtin_amdgcn_perm(wv2[2*pl],   wv2[2*pl],   selA);
            unsigned uwB = __builtin_amdgcn_perm(wv2[2*pl+1], wv2[2*pl+1], selA);
            __half2 wAh, wBh;
            __builtin_memcpy(&wAh, &uwA, 4);
            __builtin_memcpy(&wBh, &uwB, 4);
            __half2 hv;
            __builtin_memcpy(&hv, &tA.x, 4); acc0 = __hfma2(wAh, hv, acc0);
            __builtin_memcpy(&hv, &tA.y, 4); acc1 = __hfma2(wAh, hv, acc1);
            __builtin_memcpy(&hv, &tA.z, 4); acc2 = __hfma2(wAh, hv, acc2);
            __builtin_memcpy(&hv, &tA.w, 4); acc3 = __hfma2(wAh, hv, acc3);
            __builtin_memcpy(&hv, &tB.x, 4); acc0 = __hfma2(wBh, hv, acc0);
            __builtin_memcpy(&hv, &tB.y, 4); acc1 = __hfma2(wBh, hv, acc1);
            __builtin_memcpy(&hv, &tB.z, 4); acc2 = __hfma2(wBh, hv, acc2);
            __builtin_memcpy(&hv, &tB.w, 4); acc3 = __hfma2(wBh, hv, acc3);
        }
        // fold the two x-tap halves (lane <-> lane^4), scale by 1/3
        unsigned au[4];
        __half2 accs[4] = {acc0, acc1, acc2, acc3};
        #pragma unroll
        for (int j = 0; j < 4; ++j) {
            unsigned u;
            __builtin_memcpy(&u, &accs[j], 4);
            unsigned o = __shfl_xor(u, 4, 64);
            __half2 oh;
            __builtin_memcpy(&oh, &o, 4);
            __half2 r = __hmul2(__hadd2(accs[j], oh), inv3h);
            __builtin_memcpy(&au[j], &r, 4);
        }
        if ((lane & 4) == 0) {
            *reinterpret_cast<uint4*>(
                &featT[pp*16 + ((chunk ^ (pp&3)) << 2)]) =
                make_uint4(au[0], au[1], au[2], au[3]);
        }
    }
    // wave-local LDS handoff: drain own DS writes; DS is in-order per wave
    asm volatile("s_waitcnt lgkmcnt(0)" ::: "memory");

    // ---- phase 2: MLP via MFMA f32_16x16x32_f16 ----
    int w    = tid >> 6;
    int quad = lane >> 4;
    int n    = lane & 15;
    f16x8 af[4];
    {
        const uint4* wf = reinterpret_cast<const uint4*>(w1frag);
        #pragma unroll
        for (int ht = 0; ht < 4; ++ht) {
            uint4 u = wf[ht*64 + lane];
            __builtin_memcpy(&af[ht], &u, 16);
        }
    }
    #pragma unroll
    for (int p = 0; p < 4; ++p) {
        int ptile = w*4 + p;
        int pt    = ptile*16 + n;
        uint4 bu = *reinterpret_cast<const uint4*>(
            &featT[pt*16 + ((quad ^ (pt&3)) << 2)]);
        f16x8 bf;
        __builtin_memcpy(&bf, &bu, 16);
        float o0=0.f, o1=0.f, o2=0.f, o3=0.f;
        #pragma unroll
        for (int ht = 0; ht < 4; ++ht) {
            float4 bb = *reinterpret_cast<const float4*>(&b1s[ht*16 + quad*4]);
            f32x4 acc = {bb.x, bb.y, bb.z, bb.w};   // fold b1 into MFMA C
            acc = __builtin_amdgcn_mfma_f32_16x16x32_f16(af[ht], bf, acc, 0, 0, 0);
            #pragma unroll
            for (int r = 0; r < 4; ++r) {
                float hv = softplusf(acc[r]);
                float4 wr = *reinterpret_cast<const float4*>(
                    &w2s[(ht*16 + quad*4 + r)*4]);
                o0 = fmaf(hv, wr.x, o0);
                o1 = fmaf(hv, wr.y, o1);
                o2 = fmaf(hv, wr.z, o2);
                o3 = fmaf(hv, wr.w, o3);
            }
        }
        o0 += __shfl_xor(o0, 16); o0 += __shfl_xor(o0, 32);
        o1 += __shfl_xor(o1, 16); o1 += __shfl_xor(o1, 32);
        o2 += __shfl_xor(o2, 16); o2 += __shfl_xor(o2, 32);
        o3 += __shfl_xor(o3, 16); o3 += __shfl_xor(o3, 32);
        int pid2 = blockIdx.x*256 + ptile*16 + n;
        int rid2 = pid2 / 48;
        int s2   = pid2 - rid2*48;
        int slot = rid2*96 + (mode ? 48 + s2 : s2);
        if (quad == 0) {
            sigmas[slot] = 10.0f * softplusf(-10.0f * (o0 + b2[0]));
        } else {
            float oc = (quad == 1) ? o1 : (quad == 2 ? o2 : o3);
            colors[(size_t)slot*3 + (quad-1)] =
                sigmoidf(oc + b2[quad]) * 1.002f - 0.001f;
        }
    }
}

// K2: importance sampling, ONE WAVE PER RAY, fully parallel.
__global__ __launch_bounds__(256) void k_importance(
    const float* __restrict__ orig, const float* __restrict__ sigmas,
    float* __restrict__ dfine)
{
    int t    = threadIdx.x;
    int lane = t & 63;
    int rid  = blockIdx.x * 4 + (t >> 6);

    float sig = 0.0f;
    if (lane < 48) sig = sigmas[(size_t)rid*96 + lane];
    float ox = orig[rid*3+0], oy = orig[rid*3+1], oz = orig[rid*3+2];
    float cam = sqrtf(ox*ox + oy*oy + oz*oz);

    // alpha_i on lanes i = 0..46
    float sig1  = __shfl(sig, lane + 1, 64);
    float dprev = coarse_depth(cam, lane);
    float dnext = coarse_depth(cam, lane + 1);
    float a = 0.0f;
    if (lane < 47) {
        float delta = dnext - dprev;
        float dm = 0.5f*(sig + sig1);
        a = 1.0f - __expf(-delta*dm);
    }
    float v = 1.0f - a + 1e-10f;
    // inclusive product scan (Kogge-Stone)
    float p = v;
    #pragma unroll
    for (int off = 1; off < 64; off <<= 1) {
        float q = __shfl_up(p, off, 64);
        if (lane >= off) p *= q;
    }
    float T = __shfl_up(p, 1, 64);
    if (lane == 0) T = 1.0f;
    float w = a * T;
    float wprev = __shfl_up(w, 1, 64);
    if (lane == 0) wprev = 0.0f;
    float wm  = fmaxf(wprev, w);
    float wm1 = __shfl(wm, lane + 1, 64);
    float wm2 = __shfl(wm, lane + 2, 64);
    float pdf = 0.0f;
    if (lane < 45) pdf = 0.5f*(wm1 + wm2) + 0.01f + 1e-5f;
    float c = pdf;
    #pragma unroll
    for (int off = 1; off < 64; off <<= 1) {
        float q = __shfl_up(c, off, 64);
        if (lane >= off) c += q;
    }
    float S = __shfl(c, 44, 64);
    float cdfF = __shfl_up(c, 1, 64) / S;
    if (lane == 0) cdfF = 0.0f;

    float u = (float)lane * (1.0f/47.0f);
    int lo = 1, hi = 46;
    #pragma unroll
    for (int stp = 0; stp < 6; ++stp) {
        int mid = (lo + hi) >> 1;
        float cm = __shfl(cdfF, mid, 64);
        if (lo < hi) { if (cm > u) hi = mid; else lo = mid + 1; }
    }
    int ind   = lo;
    int below = ind - 1;
    int above = min(ind, 45);
    float cb = __shfl(cdfF, below, 64);
    float ca = __shfl(cdfF, above, 64);
    float bb = 0.5f*(coarse_depth(cam, below) + coarse_depth(cam, below+1));
    float ba = 0.5f*(coarse_depth(cam, above) + coarse_depth(cam, above+1));
    float d_  = ca - cb;
    float den = (d_ < 1e-5f) ? 1.0f : d_;
    if (lane < 48)
        dfine[(size_t)rid*48 + lane] = bb + (u - cb)/den * (ba - bb);
}

__device__ __forceinline__ int lb_sdf(const float* sdf, float key) {
    int lo = 0, hi = 48;
    #pragma unroll
    for (int i = 0; i < 6; ++i) {
        int mid = (lo + hi) >> 1;
        float sv = sdf[mid];
        if (lo < hi) { if (sv < key) lo = mid + 1; else hi = mid; }
    }
    return lo;
}
__device__ __forceinline__ int ub_dc(const float* dc, float key) {
    int lo = 0, hi = 48;
    #pragma unroll
    for (int i = 0; i < 6; ++i) {
        int mid = (lo + hi) >> 1;
        float dv = dc[mid];
        if (lo < hi) { if (dv <= key) lo = mid + 1; else hi = mid; }
    }
    return lo;
}

// K4: final merge + ray march, ONE WAVE PER RAY.
__global__ __launch_bounds__(256) void k_final(
    const float* __restrict__ orig,
    const float* __restrict__ colors, const float* __restrict__ sigmas,
    const float* __restrict__ dfine, float* __restrict__ out)
{
    __shared__ float lds[4][48 + 48 + 5*96 + 8];
    int t    = threadIdx.x;
    int lane = t & 63;
    int wv   = t >> 6;
    int rid  = blockIdx.x * 4 + wv;
    float* sdf = &lds[wv][0];
    float* dcl = &lds[wv][48];
    float* md  = &lds[wv][96];
    float* ms  = &lds[wv][96 + 96];
    float* mc0 = &lds[wv][96 + 2*96];
    float* mc1 = &lds[wv][96 + 3*96];
    float* mc2 = &lds[wv][96 + 4*96];

    float ox = orig[rid*3+0], oy = orig[rid*3+1], oz = orig[rid*3+2];
    float cam = sqrtf(ox*ox + oy*oy + oz*oz);

    if (lane < 48) {
        sdf[lane] = dfine[(size_t)rid*48 + lane];
        dcl[lane] = coarse_depth(cam, lane);
    }
    asm volatile("s_waitcnt lgkmcnt(0)" ::: "memory");

    {   // source 0: s = lane (0..47 coarse, 48..63 fine j=0..15)
        int s = lane;
        float sg = sigmas[(size_t)rid*96 + s];
        float q0 = colors[((size_t)rid*96 + s)*3 + 0];
        float q1 = colors[((size_t)rid*96 + s)*3 + 1];
        float q2 = colors[((size_t)rid*96 + s)*3 + 2];
        float dsv; int r;
        if (s < 48) {
            dsv = dcl[s];
            r = s + lb_sdf(sdf, dsv);
        } else {
            int j = s - 48;
            dsv = sdf[j];
            r = j + ub_dc(dcl, dsv);
        }
        md [r] = dsv; ms [r] = sg;
        mc0[r] = q0;  mc1[r] = q1;  mc2[r] = q2;
    }
    if (lane < 32) {  // source 1: s = lane+64 (fine j = lane+16)
        int j = lane + 16;
        int s = j + 48;
        float sg = sigmas[(size_t)rid*96 + s];
        float q0 = colors[((size_t)rid*96 + s)*3 + 0];
        float q1 = colors[((size_t)rid*96 + s)*3 + 1];
        float q2 = colors[((size_t)rid*96 + s)*3 + 2];
        float dsv = sdf[j];
        int r = j + ub_dc(dcl, dsv);
        md [r] = dsv; ms [r] = sg;
        mc0[r] = q0;  mc1[r] = q1;  mc2[r] = q2;
    }
    asm volatile("s_waitcnt lgkmcnt(0)" ::: "memory");

    float aA, vA, cA0, cA1, cA2, zA;
    {
        int m = lane + 1;
        float d0 = md[m-1], d1 = md[m];
        float s0 = ms[m-1], s1 = ms[m];
        aA = 1.0f - __expf(-(d1 - d0) * 0.5f*(s0 + s1));
        vA = 1.0f - aA + 1e-10f;
        cA0 = 0.5f*(mc0[m-1] + mc0[m]);
        cA1 = 0.5f*(mc1[m-1] + mc1[m]);
        cA2 = 0.5f*(mc2[m-1] + mc2[m]);
        zA  = 0.5f*(d0 + d1);
    }
    float aB = 0.0f, vB = 1.0f, cB0 = 0.0f, cB1 = 0.0f, cB2 = 0.0f, zB = 0.0f;
    if (lane < 31) {
        int m = lane + 65;
        float d0 = md[m-1], d1 = md[m];
        float s0 = ms[m-1], s1 = ms[m];
        aB = 1.0f - __expf(-(d1 - d0) * 0.5f*(s0 + s1));
        vB = 1.0f - aB + 1e-10f;
        cB0 = 0.5f*(mc0[m-1] + mc0[m]);
        cB1 = 0.5f*(mc1[m-1] + mc1[m]);
        cB2 = 0.5f*(mc2[m-1] + mc2[m]);
        zB  = 0.5f*(d0 + d1);
    }
    float pA = vA;
    #pragma unroll
    for (int off = 1; off < 64; off <<= 1) {
        float q = __shfl_up(pA, off, 64);
        if (lane >= off) pA *= q;
    }
    float TA = __shfl_up(pA, 1, 64);
    if (lane == 0) TA = 1.0f;
    float totA = __shfl(pA, 63, 64);
    float pB = vB;
    #pragma unroll
    for (int off = 1; off < 64; off <<= 1) {
        float q = __shfl_up(pB, off, 64);
        if (lane >= off) pB *= q;
    }
    float TB = __shfl_up(pB, 1, 64);
    if (lane == 0) TB = 1.0f;
    TB *= totA;

    float wA = aA * TA;
    float wB = aB * TB;
    float r0 = wA*cA0 + wB*cB0;
    float r1 = wA*cA1 + wB*cB1;
    float r2 = wA*cA2 + wB*cB2;
    float rd = wA*zA  + wB*zB;
    float rw = wA + wB;
    #pragma unroll
    for (int off = 1; off < 64; off <<= 1) {
        r0 += __shfl_xor(r0, off);
        r1 += __shfl_xor(r1, off);
        r2 += __shfl_xor(r2, off);
        rd += __shfl_xor(rd, off);
        rw += __shfl_xor(rw, off);
    }
    if (lane == 0) {
        out[rid*3+0] = r0;
        out[rid*3+1] = r1;
        out[rid*3+2] = r2;
        out[16384*3 + rid] = rd;
        out[16384*4 + rid] = rw;
    }
}

extern "C" void kernel_launch(void* const* d_in, const int* in_sizes, int n_in,
                              void* d_out, int out_size, void* d_ws, size_t ws_size,
                              hipStream_t stream)
{
    const float* planes = (const float*)d_in[0];
    const float* orig   = (const float*)d_in[1];
    const float* dirs   = (const float*)d_in[2];
    const float* w1     = (const float*)d_in[3];
    const float* b1     = (const float*)d_in[4];
    const float* w2     = (const float*)d_in[5];
    const float* b2     = (const float*)d_in[6];
    float* out = (float*)d_out;

    float* ws = (float*)d_ws;
    size_t n_sig = (size_t)NB*NR*96;
    size_t n_col = n_sig*3;
    size_t n_df  = (size_t)NB*NR*48;
    float*  sig     = ws;
    float*  col     = sig + n_sig;
    float*  dfin    = col + n_col;
    __half* planesT = (__half*)(dfin + n_df);              // 8B-aligned
    unsigned* w1frag = (unsigned*)(planesT + (size_t)12*PLANE_ELEMS);

    k_transpose<<<3073, 256, 0, stream>>>(planes, planesT, w1, w1frag);
    k_sample_mlp<<<3072, 256, 0, stream>>>(planesT, orig, dirs,
                                           w1frag, b1, w2, b2, dfin, col, sig, 0);
    k_importance<<<4096, 256, 0, stream>>>(orig, sig, dfin);
    k_sample_mlp<<<3072, 256, 0, stream>>>(planesT, orig, dirs,
                                           w1frag, b1, w2, b2, dfin, col, sig, 1);
    k_final<<<4096, 256, 0, stream>>>(orig, col, sig, dfin, out);
}